// Round 1
// baseline (645.449 us; speedup 1.0000x reference)
//
#include <hip/hip_runtime.h>
#include <hip/hip_bf16.h>

#define C_DIM 128
#define TWO_C 256
#define FC    32
#define T_DIM 512

typedef unsigned int   u32;
typedef unsigned short u16;

__device__ __forceinline__ float gelu_f(float x) {
    // exact GELU: 0.5*x*(1+erf(x/sqrt(2)))
    return 0.5f * x * (1.0f + erff(x * 0.70710678118654752440f));
}

__device__ __forceinline__ u32 f2bf_bits(float x) {
    u32 u = __float_as_uint(x);
    return (u + 0x7fffu + ((u >> 16) & 1u)) >> 16;   // RNE f32->bf16
}

// ---------- time modulation: tm = gelu(t) @ tw + tb, [B, 2C] ----------
__global__ __launch_bounds__(256) void k_tmod(const float* __restrict__ t,
                                              const float* __restrict__ tw,
                                              const float* __restrict__ tb,
                                              float* __restrict__ tm) {
    __shared__ float gt[T_DIM];
    int b = blockIdx.x;
    for (int k = threadIdx.x; k < T_DIM; k += 256)
        gt[k] = gelu_f(t[(size_t)b * T_DIM + k]);
    __syncthreads();
    int j = threadIdx.x;                 // 0..255 = 2C
    float acc = tb[j];
    for (int k = 0; k < T_DIM; ++k)
        acc += gt[k] * tw[(size_t)k * TWO_C + j];
    tm[(size_t)b * TWO_C + j] = acc;
}

// ---------- modulate: out = LN(in)*(1+scale) + shift ----------
__global__ __launch_bounds__(C_DIM) void k_mod(const float* __restrict__ in,
                                               const float* __restrict__ lns,
                                               const float* __restrict__ lnb,
                                               const float* __restrict__ tm,
                                               float* __restrict__ out, int q) {
    int n = blockIdx.x, c = threadIdx.x;     // 128 threads
    size_t o = (size_t)n * C_DIM + c;
    float v = in[o];
    float s1 = v, s2 = v * v;
#pragma unroll
    for (int off = 32; off > 0; off >>= 1) {
        s1 += __shfl_down(s1, off);
        s2 += __shfl_down(s2, off);
    }
    __shared__ float red[4];
    if ((c & 63) == 0) { red[(c >> 6) * 2] = s1; red[(c >> 6) * 2 + 1] = s2; }
    __syncthreads();
    float mean = (red[0] + red[2]) * (1.0f / C_DIM);
    float ex2  = (red[1] + red[3]) * (1.0f / C_DIM);
    float var  = ex2 - mean * mean;
    float r    = rsqrtf(var + 1e-5f);
    int b = n / q;
    float scale = tm[(size_t)b * TWO_C + c];
    float shift = tm[(size_t)b * TWO_C + C_DIM + c];
    float h = (v - mean) * r * lns[c] + lnb[c];
    out[o] = h * (1.0f + scale) + shift;
}

// ---------- counting sort by dst ----------
__global__ void k_hist(const int* __restrict__ dst, int* __restrict__ cnt, int E) {
    int e = blockIdx.x * 256 + threadIdx.x;
    if (e < E) atomicAdd(&cnt[dst[e]], 1);
}

// single-block scan over up to 32768 counters; in-place cnt->start, copy to cursor
__global__ __launch_bounds__(1024) void k_scan(int* __restrict__ data,
                                               int* __restrict__ cursor, int N) {
    __shared__ int tot[1024];
    int t = threadIdx.x;
    const int PER = 32;                      // 1024*32 = 32768 >= N
    int base = t * PER;
    int loc[PER];
    int s = 0;
#pragma unroll
    for (int i = 0; i < PER; ++i) {
        int idx = base + i;
        int v = (idx < N) ? data[idx] : 0;
        loc[i] = s; s += v;
    }
    tot[t] = s;
    __syncthreads();
    for (int off = 1; off < 1024; off <<= 1) {
        int v = (t >= off) ? tot[t - off] : 0;
        __syncthreads();
        tot[t] += v;
        __syncthreads();
    }
    int bb = (t == 0) ? 0 : tot[t - 1];
#pragma unroll
    for (int i = 0; i < PER; ++i) {
        int idx = base + i;
        if (idx < N) { int v = bb + loc[i]; data[idx] = v; cursor[idx] = v; }
    }
    if (t == 1023) data[N] = tot[1023];
}

__global__ void k_scatter(const int* __restrict__ dst, int* __restrict__ cursor,
                          int* __restrict__ sorted, int E) {
    int e = blockIdx.x * 256 + threadIdx.x;
    if (e < E) {
        int pos = atomicAdd(&cursor[dst[e]], 1);
        sorted[pos] = e;
    }
}

// ---------- edge kernel-MLP layers 1..2, written in sorted-edge order ----------
template <typename KT>
__global__ __launch_bounds__(256) void k_edgek2(
        const int* __restrict__ sorted_eid,
        const int* __restrict__ ei_src,
        const float* __restrict__ ea,
        const float* __restrict__ w1, const float* __restrict__ b1,
        const float* __restrict__ w2, const float* __restrict__ b2,
        KT* __restrict__ k2s, int* __restrict__ src_sorted, int E) {
    int p = blockIdx.x * 256 + threadIdx.x;
    if (p >= E) return;
    int eid = sorted_eid[p];
    src_sorted[p] = ei_src[eid];
    float ax = ea[(size_t)eid * 2 + 0];
    float ay = ea[(size_t)eid * 2 + 1];
    float k1[FC];
#pragma unroll
    for (int i = 0; i < FC; ++i)
        k1[i] = gelu_f(ax * w1[i] + ay * w1[FC + i] + b1[i]);
    float k2v[FC];
#pragma unroll
    for (int j = 0; j < FC; ++j) {
        float acc = b2[j];
#pragma unroll
        for (int i = 0; i < FC; ++i)
            acc += k1[i] * w2[i * FC + j];
        k2v[j] = gelu_f(acc);
    }
    if constexpr (sizeof(KT) == 4) {
        float4* o = (float4*)((float*)k2s + (size_t)p * FC);
#pragma unroll
        for (int qq = 0; qq < FC / 4; ++qq)
            o[qq] = make_float4(k2v[qq * 4 + 0], k2v[qq * 4 + 1],
                                k2v[qq * 4 + 2], k2v[qq * 4 + 3]);
    } else {
        u32 pk[FC / 2];
#pragma unroll
        for (int m = 0; m < FC / 2; ++m)
            pk[m] = f2bf_bits(k2v[2 * m]) | (f2bf_bits(k2v[2 * m + 1]) << 16);
        uint4* o = (uint4*)((u16*)k2s + (size_t)p * FC);
#pragma unroll
        for (int qq = 0; qq < FC / 8; ++qq)
            o[qq] = make_uint4(pk[qq * 4 + 0], pk[qq * 4 + 1],
                               pk[qq * 4 + 2], pk[qq * 4 + 3]);
    }
}

// ---------- conv: per-node gather; layer-3 dot in registers; residual 1 ----------
template <typename KT>
__global__ __launch_bounds__(C_DIM) void k_conv(
        const float* __restrict__ feats,
        const float* __restrict__ h_mod,
        const float* __restrict__ normv,
        const int* __restrict__ start,
        const int* __restrict__ src_sorted,
        const KT* __restrict__ k2s,
        const float* __restrict__ w3, const float* __restrict__ b3,
        const float* __restrict__ cbias,
        float* __restrict__ x) {
    int n = blockIdx.x, c = threadIdx.x;     // 128 threads, thread c owns channel c
    float w3c[FC];
#pragma unroll
    for (int j = 0; j < FC; ++j) w3c[j] = w3[j * C_DIM + c];
    int s = start[n], e = start[n + 1];
    float b3c = b3[c];
    float acc = 0.f;
    for (int p = s; p < e; ++p) {
        int src = src_sorted[p];
        float wv = b3c;
        if constexpr (sizeof(KT) == 4) {
            const float4* kr = (const float4*)((const float*)k2s + (size_t)p * FC);
#pragma unroll
            for (int q4 = 0; q4 < FC / 4; ++q4) {
                float4 kv = kr[q4];
                wv += kv.x * w3c[q4 * 4 + 0] + kv.y * w3c[q4 * 4 + 1]
                    + kv.z * w3c[q4 * 4 + 2] + kv.w * w3c[q4 * 4 + 3];
            }
        } else {
            const uint4* kr = (const uint4*)((const u16*)k2s + (size_t)p * FC);
#pragma unroll
            for (int q4 = 0; q4 < FC / 8; ++q4) {
                uint4 u = kr[q4];
                u32 vals[4] = {u.x, u.y, u.z, u.w};
#pragma unroll
                for (int m = 0; m < 4; ++m) {
                    float lo = __uint_as_float(vals[m] << 16);
                    float hi = __uint_as_float(vals[m] & 0xffff0000u);
                    wv += lo * w3c[q4 * 8 + m * 2] + hi * w3c[q4 * 8 + m * 2 + 1];
                }
            }
        }
        acc += wv * h_mod[(size_t)src * C_DIM + c];
    }
    float h = (acc + cbias[c]) / normv[n];
    size_t o = (size_t)n * C_DIM + c;
    x[o] = feats[o] + h;
}

// ---------- atomic fallback (only if ws too small for sort path) ----------
__global__ __launch_bounds__(256) void k_edge_atomic(
        const int* __restrict__ ei, const float* __restrict__ ea,
        const float* __restrict__ w1, const float* __restrict__ b1,
        const float* __restrict__ w2, const float* __restrict__ b2,
        const float* __restrict__ w3, const float* __restrict__ b3,
        const float* __restrict__ h_mod, float* __restrict__ xacc, int E) {
    int e = blockIdx.x * 256 + threadIdx.x;
    if (e >= E) return;
    int src = ei[e], dst = ei[E + e];
    float ax = ea[(size_t)e * 2], ay = ea[(size_t)e * 2 + 1];
    float k1[FC];
#pragma unroll
    for (int i = 0; i < FC; ++i) k1[i] = gelu_f(ax * w1[i] + ay * w1[FC + i] + b1[i]);
    float k2v[FC];
#pragma unroll
    for (int j = 0; j < FC; ++j) {
        float acc = b2[j];
#pragma unroll
        for (int i = 0; i < FC; ++i) acc += k1[i] * w2[i * FC + j];
        k2v[j] = gelu_f(acc);
    }
    const float* hrow = h_mod + (size_t)src * C_DIM;
    float* orow = xacc + (size_t)dst * C_DIM;
    for (int c = 0; c < C_DIM; ++c) {
        float wv = b3[c];
#pragma unroll
        for (int j = 0; j < FC; ++j) wv += k2v[j] * w3[j * C_DIM + c];
        atomicAdd(&orow[c], wv * hrow[c]);
    }
}

__global__ void k_finish(const float* __restrict__ feats, const float* __restrict__ cbias,
                         const float* __restrict__ normv, float* __restrict__ xbuf, int NC) {
    int i = blockIdx.x * 256 + threadIdx.x;
    if (i >= NC) return;
    int c = i & (C_DIM - 1);
    int n = i >> 7;
    xbuf[i] = feats[i] + (xbuf[i] + cbias[c]) / normv[n];
}

// ---------- FFN: h2 = gelu(xm @ w1 + b1) @ w2 + b2 ; out = x + h2 ----------
#define FFN_ROWS 16
__global__ __launch_bounds__(256) void k_ffn(const float* __restrict__ xm,
                                             const float* __restrict__ x,
                                             const float* __restrict__ w1,
                                             const float* __restrict__ b1,
                                             const float* __restrict__ w2,
                                             const float* __restrict__ b2,
                                             float* __restrict__ out, int N) {
    __shared__ __align__(16) float sxm[FFN_ROWS * C_DIM];   // 8 KB
    __shared__ __align__(16) float sm[FFN_ROWS * TWO_C];    // 16 KB
    int tid = threadIdx.x;                                   // 256 threads
    size_t base = (size_t)blockIdx.x * FFN_ROWS;
    for (int idx = tid; idx < FFN_ROWS * C_DIM; idx += 256)
        sxm[idx] = xm[base * C_DIM + idx];
    __syncthreads();
    { // layer 1: thread j computes m[i][j] for all 16 rows
        float acc[FFN_ROWS];
        float bj = b1[tid];
#pragma unroll
        for (int i = 0; i < FFN_ROWS; ++i) acc[i] = bj;
        for (int k = 0; k < C_DIM; k += 4) {
            float wa = w1[(size_t)(k + 0) * TWO_C + tid];
            float wb = w1[(size_t)(k + 1) * TWO_C + tid];
            float wc = w1[(size_t)(k + 2) * TWO_C + tid];
            float wd = w1[(size_t)(k + 3) * TWO_C + tid];
#pragma unroll
            for (int i = 0; i < FFN_ROWS; ++i) {
                float4 xv = *(const float4*)&sxm[i * C_DIM + k];
                acc[i] += xv.x * wa + xv.y * wb + xv.z * wc + xv.w * wd;
            }
        }
#pragma unroll
        for (int i = 0; i < FFN_ROWS; ++i) sm[i * TWO_C + tid] = gelu_f(acc[i]);
    }
    __syncthreads();
    { // layer 2: c = tid&127, group g = tid>>7 handles rows g*8..g*8+7
        int c = tid & (C_DIM - 1), g = tid >> 7;
        float acc[8];
        float bc = b2[c];
#pragma unroll
        for (int i = 0; i < 8; ++i) acc[i] = bc;
        for (int k = 0; k < TWO_C; k += 4) {
            float ua = w2[(size_t)(k + 0) * C_DIM + c];
            float ub = w2[(size_t)(k + 1) * C_DIM + c];
            float uc = w2[(size_t)(k + 2) * C_DIM + c];
            float ud = w2[(size_t)(k + 3) * C_DIM + c];
#pragma unroll
            for (int i = 0; i < 8; ++i) {
                float4 mv = *(const float4*)&sm[(g * 8 + i) * TWO_C + k];
                acc[i] += mv.x * ua + mv.y * ub + mv.z * uc + mv.w * ud;
            }
        }
#pragma unroll
        for (int i = 0; i < 8; ++i) {
            size_t n = base + g * 8 + i;
            if (n < (size_t)N) {
                size_t o = n * C_DIM + c;
                out[o] = x[o] + acc[i];
            }
        }
    }
}

extern "C" void kernel_launch(void* const* d_in, const int* in_sizes, int n_in,
                              void* d_out, int out_size, void* d_ws, size_t ws_size,
                              hipStream_t stream) {
    const float* feats = (const float*)d_in[0];
    const int*   ei    = (const int*)d_in[1];
    const float* ea    = (const float*)d_in[2];
    const float* t     = (const float*)d_in[3];
    const float* normv = (const float*)d_in[4];
    const float* ln1s  = (const float*)d_in[5];
    const float* ln1b  = (const float*)d_in[6];
    const float* ln2s  = (const float*)d_in[7];
    const float* ln2b  = (const float*)d_in[8];
    const float* tw1   = (const float*)d_in[9];
    const float* tb1   = (const float*)d_in[10];
    const float* tw2   = (const float*)d_in[11];
    const float* tb2   = (const float*)d_in[12];
    const float* kw1   = (const float*)d_in[13];
    const float* kb1   = (const float*)d_in[14];
    const float* kw2   = (const float*)d_in[15];
    const float* kb2   = (const float*)d_in[16];
    const float* kw3   = (const float*)d_in[17];
    const float* kb3   = (const float*)d_in[18];
    const float* cbias = (const float*)d_in[19];
    const float* mw1   = (const float*)d_in[20];
    const float* mb1   = (const float*)d_in[21];
    const float* mw2   = (const float*)d_in[22];
    const float* mb2   = (const float*)d_in[23];
    float* out = (float*)d_out;

    const int N = in_sizes[0] / C_DIM;
    const int E = in_sizes[1] / 2;
    const int B = in_sizes[3] / T_DIM;
    const int q = N / B;

    // ---- workspace layout ----
    char* wp = (char*)d_ws;
    auto alloc = [&](size_t bytes) -> char* {
        char* p = wp; wp += (bytes + 255) & ~(size_t)255; return p;
    };
    float* tm1        = (float*)alloc((size_t)B * TWO_C * 4);
    float* tm2        = (float*)alloc((size_t)B * TWO_C * 4);
    float* h_mod      = (float*)alloc((size_t)N * C_DIM * 4);
    float* xbuf       = (float*)alloc((size_t)N * C_DIM * 4);
    size_t atomic_need = (size_t)(wp - (char*)d_ws);
    int*   cnt        = (int*)alloc(((size_t)N + 1) * 4);   // becomes start[] after scan
    int*   cursor     = (int*)alloc((size_t)N * 4);
    int*   sorted     = (int*)alloc((size_t)E * 4);
    int*   src_sorted = (int*)alloc((size_t)E * 4);
    size_t fixed = (size_t)(wp - (char*)d_ws);
    bool can_f32 = ws_size >= fixed + (size_t)E * FC * 4;
    bool can_b16 = ws_size >= fixed + (size_t)E * FC * 2;
    void* k2s = (void*)alloc((size_t)E * FC * (can_f32 ? 4 : 2));

    const int eb = (E + 255) / 256;

    // time modulations + pre-conv modulate (common to all paths)
    k_tmod<<<B, 256, 0, stream>>>(t, tw1, tb1, tm1);
    k_tmod<<<B, 256, 0, stream>>>(t, tw2, tb2, tm2);
    k_mod<<<N, C_DIM, 0, stream>>>(feats, ln1s, ln1b, tm1, h_mod, q);

    if (can_f32 || can_b16) {
        hipMemsetAsync(cnt, 0, ((size_t)N + 1) * 4, stream);
        k_hist<<<eb, 256, 0, stream>>>(ei + E, cnt, E);
        k_scan<<<1, 1024, 0, stream>>>(cnt, cursor, N);
        k_scatter<<<eb, 256, 0, stream>>>(ei + E, cursor, sorted, E);
        if (can_f32) {
            k_edgek2<float><<<eb, 256, 0, stream>>>(sorted, ei, ea, kw1, kb1, kw2, kb2,
                                                    (float*)k2s, src_sorted, E);
            k_conv<float><<<N, C_DIM, 0, stream>>>(feats, h_mod, normv, cnt, src_sorted,
                                                   (const float*)k2s, kw3, kb3, cbias, xbuf);
        } else {
            k_edgek2<u16><<<eb, 256, 0, stream>>>(sorted, ei, ea, kw1, kb1, kw2, kb2,
                                                  (u16*)k2s, src_sorted, E);
            k_conv<u16><<<N, C_DIM, 0, stream>>>(feats, h_mod, normv, cnt, src_sorted,
                                                 (const u16*)k2s, kw3, kb3, cbias, xbuf);
        }
    } else {
        // last-resort atomic path (needs only ~32.3 MB of ws)
        (void)atomic_need;
        hipMemsetAsync(xbuf, 0, (size_t)N * C_DIM * 4, stream);
        k_edge_atomic<<<eb, 256, 0, stream>>>(ei, ea, kw1, kb1, kw2, kb2, kw3, kb3,
                                              h_mod, xbuf, E);
        int nc = N * C_DIM;
        k_finish<<<(nc + 255) / 256, 256, 0, stream>>>(feats, cbias, normv, xbuf, nc);
    }

    // post-conv modulate (reuse h_mod buffer) + FFN + residual 2
    k_mod<<<N, C_DIM, 0, stream>>>(xbuf, ln2s, ln2b, tm2, h_mod, q);
    k_ffn<<<(N + FFN_ROWS - 1) / FFN_ROWS, 256, 0, stream>>>(h_mod, xbuf, mw1, mb1,
                                                             mw2, mb2, out, N);
}